// Round 17
// baseline (102.095 us; speedup 1.0000x reference)
//
#include <hip/hip_runtime.h>
#include <hip/hip_bf16.h>
#include <stdint.h>

typedef __attribute__((ext_vector_type(4))) float fv4;
typedef __attribute__((ext_vector_type(4))) short sv4;
typedef __attribute__((ext_vector_type(8))) short sv8;

typedef __attribute__((address_space(3))) float lds_f;
typedef __attribute__((address_space(1))) const float glb_f;

#define SCHUNK 2048
#define NIT 16                   // tiles per wave
#define NWV 2                    // waves per block
#define SPAN (NWV * NIT * 16)    // 512 facets per block

static __device__ __forceinline__ short f2bf(float f) {
  __hip_bfloat16 h = __float2bfloat16(f);   // HW v_cvt, RNE
  union { __hip_bfloat16 h; short s; } u; u.h = h;
  return u.s;
}

// ---------------- scan kernels (R1-validated) ----------------
__global__ __launch_bounds__(256) void scan1(const int* __restrict__ num, int nf,
                                             int* __restrict__ bsum) {
  __shared__ int sd[256];
  int b = blockIdx.x, tid = threadIdx.x;
  int base = b * SCHUNK + tid * 8;
  int s = 0;
#pragma unroll
  for (int j = 0; j < 8; ++j) { int i = base + j; if (i < nf) s += num[i]; }
  sd[tid] = s; __syncthreads();
  for (int st = 128; st > 0; st >>= 1) {
    if (tid < st) sd[tid] += sd[tid + st];
    __syncthreads();
  }
  if (tid == 0) bsum[b] = sd[0];
}

__global__ __launch_bounds__(256) void scan2(int* __restrict__ bsum, int nb) {
  __shared__ int sd[256];
  int tid = threadIdx.x;
  int v = (tid < nb) ? bsum[tid] : 0;
  sd[tid] = v; __syncthreads();
  for (int off = 1; off < 256; off <<= 1) {
    int t = (tid >= off) ? sd[tid - off] : 0;
    __syncthreads();
    sd[tid] += t;
    __syncthreads();
  }
  if (tid < nb) bsum[tid] = sd[tid] - v;   // exclusive prefix
}

__global__ __launch_bounds__(256) void scan3(const int* __restrict__ num, int nf,
                                             const int* __restrict__ bsum,
                                             int* __restrict__ offsets) {
  __shared__ int sc_[256];
  int b = blockIdx.x, tid = threadIdx.x;
  int base = b * SCHUNK + tid * 8;
  int loc[8]; int s = 0;
#pragma unroll
  for (int j = 0; j < 8; ++j) {
    loc[j] = (base + j < nf) ? num[base + j] : 0;
    s += loc[j];
  }
  sc_[tid] = s; __syncthreads();
  for (int off = 1; off < 256; off <<= 1) {
    int t = (tid >= off) ? sc_[tid - off] : 0;
    __syncthreads();
    sc_[tid] += t;
    __syncthreads();
  }
  int run = bsum[b] + sc_[tid] - s;
#pragma unroll
  for (int j = 0; j < 8; ++j) {
    if (base + j < nf) offsets[base + j] = run;
    run += loc[j];
  }
  if (b == gridDim.x - 1 && tid == 255) offsets[nf] = run;
}

// ---------------- prep: W -> bf16 w2g[o*96 + k*32 + c] (R8-validated) ----------------
__global__ __launch_bounds__(256) void k_prep(const float* __restrict__ W,
                                              short* __restrict__ w2g) {
  for (int i = threadIdx.x; i < 3072; i += 256) {
    int o = i / 96;
    int ck = i - o * 96;
    int k = ck >> 5, c = ck & 31;
    w2g[o * 96 + ck] = f2bf(W[o * 96 + c * 3 + k]);
  }
}

#define WAITN_(N) do { \
  asm volatile("s_waitcnt vmcnt(" #N ")" ::: "memory"); \
  __builtin_amdgcn_sched_barrier(0); \
} while (0)
#define WAITN(N) WAITN_(N)

// stage x rows [3*f0t,+48) + bary floats [9*f0t,+144) into wave buffer BUF (R15/R16-validated)
#define STAGE(T, BUF) do { \
  if (can_stage) { \
    const int f0t_ = blk0w + (T) * 16; \
    long r0_ = 3L * f0t_; \
    long br_ = (r0_ + 48 <= (long)nt) ? r0_ : (long)nt - 48; \
    const float* gx_ = x + br_ * 32; \
    float* lb_ = &Xs[wv][BUF][0]; \
    _Pragma("unroll") \
    for (int i_ = 0; i_ < 6; ++i_) { \
      int L_ = i_ * 64 + lane; \
      int G_ = L_ ^ ((L_ >> 3) & 7); \
      __builtin_amdgcn_global_load_lds((glb_f*)(gx_ + G_ * 4), (lds_f*)(lb_ + i_ * 256), 16, 0, 0); \
    } \
    const float* gb_ = bary + br_ * 3; \
    if (lane < 36) \
      __builtin_amdgcn_global_load_lds((glb_f*)(gb_ + lane * 4), (lds_f*)(&Bs[wv][BUF][0]), 16, 0, 0); \
  } \
} while (0)

// offsets prefetch (R13-validated)
#define LOADR(S, T) do { \
  const int f_ = blk0w + (T) * 16 + rowl; \
  const int fa_ = f_ < nf ? f_ : nf; \
  const int fb_ = (f_ + 1) < nf ? (f_ + 1) : nf; \
  st_##S = offsets[fa_]; \
  en_##S = offsets[fb_]; \
} while (0)

// one pipeline part: wait(WN), compute tile T from buf BUF, coalesced store, optional stage T+4
#define PART(S, T, BUF, STG, WN) do { \
  WAITN(WN); \
  const int f0t = blk0w + (T) * 16; \
  const int f_ = f0t + rowl; \
  const int nm_my = en_##S - st_##S; \
  const bool dense_ = can_stage && (3L * f0t + 48 <= (long)nt); \
  const bool dense_st = (f0t + 16 <= nf); \
  float z0[8], z1[8], z2[8]; \
  _Pragma("unroll") \
  for (int j = 0; j < 8; ++j) { z0[j] = 0.f; z1[j] = 0.f; z2[j] = 0.f; } \
  if (dense_ && nm_my == 3 && st_##S == 3 * f_) { \
    const float* Xb_ = &Xs[wv][BUF][0]; \
    const float* bb_ = &Bs[wv][BUF][9 * rowl]; \
    _Pragma("unroll") \
    for (int s_ = 0; s_ < 3; ++s_) { \
      int row_ = 3 * rowl + s_; \
      int sw_ = row_ & 7; \
      fv4 xa = *(const fv4*)(Xb_ + (((row_ * 8 + grp) ^ sw_) << 2)); \
      fv4 xb = *(const fv4*)(Xb_ + (((row_ * 8 + 4 + grp) ^ sw_) << 2)); \
      float b0_ = bb_[3 * s_ + 0]; \
      float b1_ = bb_[3 * s_ + 1]; \
      float b2_ = bb_[3 * s_ + 2]; \
      _Pragma("unroll") \
      for (int j = 0; j < 4; ++j) { \
        z0[j]     += xa[j] * b0_; z1[j]     += xa[j] * b1_; z2[j]     += xa[j] * b2_; \
        z0[4 + j] += xb[j] * b0_; z1[4 + j] += xb[j] * b1_; z2[4 + j] += xb[j] * b2_; \
      } \
    } \
  } else { \
    for (int t2 = st_##S; t2 < en_##S; ++t2) { \
      const float* xp = x + (size_t)t2 * 32; \
      fv4 xa = *(const fv4*)(xp + cb_lo); \
      fv4 xb = *(const fv4*)(xp + cb_hi); \
      const float* bpp = bary + (size_t)t2 * 3; \
      float b0_ = bpp[0], b1_ = bpp[1], b2_ = bpp[2]; \
      _Pragma("unroll") \
      for (int j = 0; j < 4; ++j) { \
        z0[j]     += xa[j] * b0_; z1[j]     += xa[j] * b1_; z2[j]     += xa[j] * b2_; \
        z0[4 + j] += xb[j] * b0_; z1[4 + j] += xb[j] * b1_; z2[4 + j] += xb[j] * b2_; \
      } \
    } \
  } \
  fv4 acc0 = (fv4){0.f, 0.f, 0.f, 0.f}; \
  fv4 acc1 = (fv4){0.f, 0.f, 0.f, 0.f}; \
  _Pragma("unroll") \
  for (int kb = 0; kb < 3; ++kb) { \
    sv8 afr; \
    _Pragma("unroll") \
    for (int j = 0; j < 4; ++j) { \
      float lo = (kb == 0) ? z0[j]     : (kb == 1) ? z1[j]     : z2[j]; \
      float hi = (kb == 0) ? z0[4 + j] : (kb == 1) ? z1[4 + j] : z2[4 + j]; \
      afr[j]     = f2bf(lo); \
      afr[4 + j] = f2bf(hi); \
    } \
    acc0 = __builtin_amdgcn_mfma_f32_16x16x32_bf16(afr, bfrA[kb], acc0, 0, 0, 0); \
    acc1 = __builtin_amdgcn_mfma_f32_16x16x32_bf16(afr, bfrB[kb], acc1, 0, 0, 0); \
  } \
  float* yw = &Yt[wv][0]; \
  _Pragma("unroll") \
  for (int r = 0; r < 4; ++r) { \
    int row = grp * 4 + r; \
    int fr = f0t + row; \
    int nm = __shfl(nm_my, row, 64); \
    float inv = 1.0f / (float)(nm > 1 ? nm : 1); \
    float v0 = fmaxf(acc0[r] * inv + bo0, 0.f); \
    float v1 = fmaxf(acc1[r] * inv + bo1, 0.f); \
    if (dense_st) { \
      yw[row * 32 + rowl]      = v0; \
      yw[row * 32 + 16 + rowl] = v1; \
      s1l += v0; s2l += v0 * v0; \
      s1h += v1; s2h += v1 * v1; \
    } else if (fr < nf) { \
      out[fr * 32 + rowl]      = v0; \
      out[fr * 32 + 16 + rowl] = v1; \
      s1l += v0; s2l += v0 * v0; \
      s1h += v1; s2h += v1 * v1; \
    } \
  } \
  if (dense_st) { \
    __builtin_amdgcn_wave_barrier(); \
    const float* yr = &Yt[wv][0]; \
    fv4 o0 = *(const fv4*)(yr + lane * 4); \
    fv4 o1 = *(const fv4*)(yr + 256 + lane * 4); \
    float* op = out + (size_t)f0t * 32; \
    *(fv4*)(op + lane * 4)       = o0; \
    *(fv4*)(op + 256 + lane * 4) = o1; \
    __builtin_amdgcn_wave_barrier(); \
  } \
  if (STG) { \
    __builtin_amdgcn_sched_barrier(0); \
    STAGE((T) + 4, BUF); \
    LOADR(S, (T) + 4); \
  } \
} while (0)

// ---------------- main: 4-deep prefetch pipeline, 2-wave blocks, no block barriers ----------------
__global__ __launch_bounds__(128) void k_main(
    const float* __restrict__ x, const float* __restrict__ bary,
    const short* __restrict__ w2g, const float* __restrict__ bias,
    const int* __restrict__ offsets, float* __restrict__ out,
    float* __restrict__ partials, int nf, int nt, int nw)
{
  __shared__ __align__(16) float Xs[NWV][4][1536];   // 48 KiB: x 4-deep buffers
  __shared__ __align__(16) float Bs[NWV][4][256];    // 8 KiB: bary 4-deep buffers
  __shared__ __align__(16) float Yt[NWV][512];       // 4 KiB: out-tile transpose

  const int tid = threadIdx.x;
  const int lane = tid & 63;
  const int wv = tid >> 6;

  const int rowl = lane & 15;          // facet-in-tile AND output col
  const int grp = lane >> 4;           // fragment k-quad / epilogue row group
  const int cb_lo = grp * 4;           // fold channels low quad (generic path)
  const int cb_hi = grp * 4 + 16;      // fold channels high quad (generic path)
  const int blk0w = blockIdx.x * SPAN + wv * (NIT * 16);

  // ---- hoist B-fragments from global w2g (R14-validated) ----
  sv8 bfrA[3], bfrB[3];
#pragma unroll
  for (int kb = 0; kb < 3; ++kb) {
    const int cko = kb * 32 + grp * 4;
    {
      const short* wr = w2g + rowl * 96 + cko;
      sv4 lo = *(const sv4*)(wr), hi = *(const sv4*)(wr + 16);
#pragma unroll
      for (int j = 0; j < 4; ++j) { bfrA[kb][j] = lo[j]; bfrA[kb][4 + j] = hi[j]; }
    }
    {
      const short* wr = w2g + (16 + rowl) * 96 + cko;
      sv4 lo = *(const sv4*)(wr), hi = *(const sv4*)(wr + 16);
#pragma unroll
      for (int j = 0; j < 4; ++j) { bfrB[kb][j] = lo[j]; bfrB[kb][4 + j] = hi[j]; }
    }
  }

  float bo0 = bias[rowl];
  float bo1 = bias[16 + rowl];
  float s1l = 0.f, s1h = 0.f, s2l = 0.f, s2h = 0.f;

  const bool can_stage = (nt >= 48);   // wave-uniform

  int st_A, en_A, st_B, en_B, st_C, en_C, st_D, en_D;

  // prologue: 4 stages in flight before first compute
  STAGE(0, 0); LOADR(A, 0);
  STAGE(1, 1); LOADR(B, 1);
  STAGE(2, 2); LOADR(C, 2);
  STAGE(3, 3); LOADR(D, 3);

  // ledger-derived waits (conservative side): parts 0-3: 21; steady: 27; tail: 20/13/6
  PART(A, 0, 0, 1, 21);
  PART(B, 1, 1, 1, 21);
  PART(C, 2, 2, 1, 21);
  PART(D, 3, 3, 1, 21);
#pragma unroll
  for (int t = 4; t < NIT - 4; t += 4) {
    PART(A, t, 0, 1, 27);
    PART(B, t + 1, 1, 1, 27);
    PART(C, t + 2, 2, 1, 27);
    PART(D, t + 3, 3, 1, 27);
  }
  PART(A, NIT - 4, 0, 0, 27);
  PART(B, NIT - 3, 1, 0, 20);
  PART(C, NIT - 2, 2, 0, 13);
  PART(D, NIT - 1, 3, 0, 6);

  // ---- per-wave stats -> one partials column (R8-validated reduce) ----
  s1l += __shfl_xor(s1l, 16, 64); s1l += __shfl_xor(s1l, 32, 64);
  s1h += __shfl_xor(s1h, 16, 64); s1h += __shfl_xor(s1h, 32, 64);
  s2l += __shfl_xor(s2l, 16, 64); s2l += __shfl_xor(s2l, 32, 64);
  s2h += __shfl_xor(s2h, 16, 64); s2h += __shfl_xor(s2h, 32, 64);
  if (grp == 0) {
    int w = blockIdx.x * NWV + wv;
    partials[(long)(rowl)      * nw + w] = s1l;
    partials[(long)(16 + rowl) * nw + w] = s1h;
    partials[(long)(32 + rowl) * nw + w] = s2l;
    partials[(long)(48 + rowl) * nw + w] = s2h;
  }
}

// ---------------- reduce partials -> stats[64] ----------------
__global__ __launch_bounds__(256) void k_reduce(const float* __restrict__ partials,
                                                int nw, float* __restrict__ stats) {
  __shared__ float sd[256];
  int c = blockIdx.x;
  const float* p = partials + (long)c * nw;
  float s = 0.f;
  for (int i = threadIdx.x; i < nw; i += 256) s += p[i];
  sd[threadIdx.x] = s; __syncthreads();
  for (int st = 128; st > 0; st >>= 1) {
    if (threadIdx.x < st) sd[threadIdx.x] += sd[threadIdx.x + st];
    __syncthreads();
  }
  if (threadIdx.x == 0) stats[c] = sd[0];
}

// ---------------- BN apply, in place on out ----------------
__global__ __launch_bounds__(256) void k_bn(float* __restrict__ out,
                                            const float* __restrict__ stats,
                                            const float* __restrict__ gamma,
                                            const float* __restrict__ beta, int nf) {
  __shared__ float sc[32], sh[32];
  if (threadIdx.x < 32) {
    int o = threadIdx.x;
    float inv_n = 1.0f / (float)nf;
    float mean = stats[o] * inv_n;
    float var = stats[32 + o] * inv_n - mean * mean;
    float rstd = rsqrtf(var + 1e-5f);
    float g = gamma[o] * rstd;
    sc[o] = g;
    sh[o] = beta[o] - mean * g;
  }
  __syncthreads();
  long total4 = (long)nf * 8;
  long idx0 = (long)blockIdx.x * 256 + threadIdx.x;
  int ob = ((int)idx0 & 7) * 4;           // constant per thread (stride % 8 == 0)
  fv4 scv = *(const fv4*)&sc[ob];
  fv4 shv = *(const fv4*)&sh[ob];
  for (long idx = idx0; idx < total4; idx += (long)gridDim.x * 256) {
    fv4 v = *((const fv4*)out + idx);
    v = v * scv + shv;
    *((fv4*)out + idx) = v;
  }
}

extern "C" void kernel_launch(void* const* d_in, const int* in_sizes, int n_in,
                              void* d_out, int out_size, void* d_ws, size_t ws_size,
                              hipStream_t stream) {
  const float* x     = (const float*)d_in[0];
  const float* bary  = (const float*)d_in[1];
  const int*   numt  = (const int*)d_in[2];
  const float* W     = (const float*)d_in[3];
  const float* bias  = (const float*)d_in[4];
  const float* gamma = (const float*)d_in[5];
  const float* beta  = (const float*)d_in[6];
  float* out = (float*)d_out;

  const int nf   = in_sizes[2];
  const int nt   = in_sizes[0] / 32;      // total samples
  const int nblk = (nf + SPAN - 1) / SPAN;
  const int nw   = nblk * NWV;            // one partials column per wave
  const int nbS  = (nf + SCHUNK - 1) / SCHUNK;

  char* w = (char*)d_ws;
  int* offsets = (int*)w;
  size_t off1 = (4UL * (size_t)(nf + 1) + 255) & ~255UL;
  int* bsum = (int*)(w + off1);
  size_t off2 = (off1 + 4UL * (size_t)nbS + 255) & ~255UL;
  short* w2g = (short*)(w + off2);
  size_t off3 = (off2 + 2UL * 3072UL + 255) & ~255UL;
  float* partials = (float*)(w + off3);
  size_t off4 = (off3 + 4UL * 64UL * (size_t)nw + 255) & ~255UL;
  float* stats = (float*)(w + off4);

  scan1<<<nbS, 256, 0, stream>>>(numt, nf, bsum);
  scan2<<<1, 256, 0, stream>>>(bsum, nbS);
  scan3<<<nbS, 256, 0, stream>>>(numt, nf, bsum, offsets);
  k_prep<<<1, 256, 0, stream>>>(W, w2g);
  k_main<<<nblk, NWV * 64, 0, stream>>>(x, bary, w2g, bias, offsets, out, partials, nf, nt, nw);
  k_reduce<<<64, 256, 0, stream>>>(partials, nw, stats);
  k_bn<<<2048, 256, 0, stream>>>(out, stats, gamma, beta, nf);
}

// Round 18
// 96.910 us; speedup vs baseline: 1.0535x; 1.0535x over previous
//
#include <hip/hip_runtime.h>
#include <hip/hip_bf16.h>
#include <stdint.h>

typedef __attribute__((ext_vector_type(4))) float fv4;
typedef float fv4u __attribute__((ext_vector_type(4), aligned(4)));   // 4B-aligned vector load
typedef __attribute__((ext_vector_type(4))) short sv4;
typedef __attribute__((ext_vector_type(8))) short sv8;

#define SCHUNK 2048
#define NIT 8             // tiles per wave
#define SPAN (64 * NIT)   // facets per block
#define PZB 108           // W2 row pitch (shorts), validated

static __device__ __forceinline__ short f2bf(float f) {
  __hip_bfloat16 h = __float2bfloat16(f);   // HW v_cvt, RNE
  union { __hip_bfloat16 h; short s; } u; u.h = h;
  return u.s;
}

// ---------------- scan: offsets from num_texture (R1-validated) ----------------
__global__ __launch_bounds__(256) void scan1(const int* __restrict__ num, int nf,
                                             int* __restrict__ bsum) {
  __shared__ int sd[256];
  int b = blockIdx.x, tid = threadIdx.x;
  int base = b * SCHUNK + tid * 8;
  int s = 0;
#pragma unroll
  for (int j = 0; j < 8; ++j) { int i = base + j; if (i < nf) s += num[i]; }
  sd[tid] = s; __syncthreads();
  for (int st = 128; st > 0; st >>= 1) {
    if (tid < st) sd[tid] += sd[tid + st];
    __syncthreads();
  }
  if (tid == 0) bsum[b] = sd[0];
}

__global__ __launch_bounds__(256) void scan2(int* __restrict__ bsum, int nb) {
  __shared__ int sd[256];
  int tid = threadIdx.x;
  int v = (tid < nb) ? bsum[tid] : 0;
  sd[tid] = v; __syncthreads();
  for (int off = 1; off < 256; off <<= 1) {
    int t = (tid >= off) ? sd[tid - off] : 0;
    __syncthreads();
    sd[tid] += t;
    __syncthreads();
  }
  if (tid < nb) bsum[tid] = sd[tid] - v;   // exclusive prefix
}

__global__ __launch_bounds__(256) void scan3(const int* __restrict__ num, int nf,
                                             const int* __restrict__ bsum,
                                             int* __restrict__ offsets) {
  __shared__ int sc_[256];
  int b = blockIdx.x, tid = threadIdx.x;
  int base = b * SCHUNK + tid * 8;
  int loc[8]; int s = 0;
#pragma unroll
  for (int j = 0; j < 8; ++j) {
    loc[j] = (base + j < nf) ? num[base + j] : 0;
    s += loc[j];
  }
  sc_[tid] = s; __syncthreads();
  for (int off = 1; off < 256; off <<= 1) {
    int t = (tid >= off) ? sc_[tid - off] : 0;
    __syncthreads();
    sc_[tid] += t;
    __syncthreads();
  }
  int run = bsum[b] + sc_[tid] - s;
#pragma unroll
  for (int j = 0; j < 8; ++j) {
    if (base + j < nf) offsets[base + j] = run;
    run += loc[j];
  }
  if (b == gridDim.x - 1 && tid == 255) offsets[nf] = run;
}

// ---------------- main: lane folds its own A-fragment; B-frags read per-tile from LDS ----------------
// Lane (rowl, grp) folds facet f0t+rowl over channels {4g..4g+4} u {4g+16..4g+20}  (R12/R13-validated)
__global__ __launch_bounds__(256, 5) void k_main(
    const float* __restrict__ x, const float* __restrict__ bary,
    const float* __restrict__ W, const float* __restrict__ bias,
    const int* __restrict__ offsets, float* __restrict__ out,
    float* __restrict__ partials, int nf, int nt, int nw)
{
  __shared__ short W2[32 * PZB];       // 6912 B; read-only after prologue

  const int tid = threadIdx.x;
  const int lane = tid & 63;
  const int wv = tid >> 6;

  // ---- prologue: stage W2[o*PZB + k*32 + c] = bf16(W[o*96 + c*3 + k]) (validated) ----
  for (int idx = tid; idx < 3072; idx += 256) {
    int o = idx / 96;
    int ck = idx - o * 96;
    int k = ck >> 5, c = ck & 31;
    W2[o * PZB + ck] = f2bf(W[o * 96 + c * 3 + k]);
  }
  __syncthreads();   // the ONLY block barrier

  const int rowl = lane & 15;          // facet-in-tile AND output col
  const int grp = lane >> 4;           // fragment k-quad / epilogue row group
  const int cb_lo = grp * 4;           // fold channels low quad
  const int cb_hi = grp * 4 + 16;      // fold channels high quad
  const int blk0 = blockIdx.x * SPAN;

  float bo0 = bias[rowl];
  float bo1 = bias[16 + rowl];
  float s1l = 0.f, s1h = 0.f, s2l = 0.f, s2h = 0.f;

#pragma unroll 2
  for (int t = 0; t < NIT; ++t) {
    const int f0t = blk0 + t * 64 + wv * 16;
    const int f = f0t + rowl;
    const int fa = f < nf ? f : nf;
    const int fb = (f + 1) < nf ? (f + 1) : nf;

    // ---- batched loads: offsets AND speculative x/bary (R10/R13-validated pattern) ----
    const int st = offsets[fa];
    const int en = offsets[fb];
    const int s3 = 3 * f;
    const int sbase = (f < nf && s3 + 3 <= nt) ? s3 : 0;   // clamped, never OOB
    const float* xp0 = x + (size_t)(sbase + 0) * 32;
    const float* xp1 = x + (size_t)(sbase + 1) * 32;
    const float* xp2 = x + (size_t)(sbase + 2) * 32;
    fv4 x0a = *(const fv4*)(xp0 + cb_lo), x0b = *(const fv4*)(xp0 + cb_hi);
    fv4 x1a = *(const fv4*)(xp1 + cb_lo), x1b = *(const fv4*)(xp1 + cb_hi);
    fv4 x2a = *(const fv4*)(xp2 + cb_lo), x2b = *(const fv4*)(xp2 + cb_hi);
    // bary rows for samples sbase..sbase+2 are 9 contiguous floats (R13-validated)
    const float* bp = bary + (size_t)sbase * 3;
    fv4u bv0 = *(const fv4u*)(bp);       // b00 b01 b02 b10
    fv4u bv1 = *(const fv4u*)(bp + 4);   // b11 b12 b20 b21
    float b22 = bp[8];
    float b00 = bv0[0], b01 = bv0[1], b02 = bv0[2];
    float b10 = bv0[3], b11 = bv1[0], b12 = bv1[1];
    float b20 = bv1[2], b21 = bv1[3];

    const int nm_my = en - st;

    // ---- fold (R12/R13-validated FMA pattern; channel set = this lane's A-fragment) ----
    float z0[8], z1[8], z2[8];
#pragma unroll
    for (int j = 0; j < 8; ++j) { z0[j] = 0.f; z1[j] = 0.f; z2[j] = 0.f; }

    if (nm_my == 3 && st == s3) {
#pragma unroll
      for (int j = 0; j < 4; ++j) {
        z0[j]     += x0a[j] * b00; z1[j]     += x0a[j] * b01; z2[j]     += x0a[j] * b02;
        z0[4 + j] += x0b[j] * b00; z1[4 + j] += x0b[j] * b01; z2[4 + j] += x0b[j] * b02;
      }
#pragma unroll
      for (int j = 0; j < 4; ++j) {
        z0[j]     += x1a[j] * b10; z1[j]     += x1a[j] * b11; z2[j]     += x1a[j] * b12;
        z0[4 + j] += x1b[j] * b10; z1[4 + j] += x1b[j] * b11; z2[4 + j] += x1b[j] * b12;
      }
#pragma unroll
      for (int j = 0; j < 4; ++j) {
        z0[j]     += x2a[j] * b20; z1[j]     += x2a[j] * b21; z2[j]     += x2a[j] * b22;
        z0[4 + j] += x2b[j] * b20; z1[4 + j] += x2b[j] * b21; z2[4 + j] += x2b[j] * b22;
      }
    } else {
      // generic ragged path (validated FMA pattern, same channel set)
      for (int t2 = st; t2 < en; ++t2) {
        const float* xp = x + (size_t)t2 * 32;
        fv4 xa = *(const fv4*)(xp + cb_lo);
        fv4 xb = *(const fv4*)(xp + cb_hi);
        const float* bpp = bary + (size_t)t2 * 3;
        float b0 = bpp[0], b1 = bpp[1], b2 = bpp[2];
#pragma unroll
        for (int j = 0; j < 4; ++j) {
          z0[j]     += xa[j] * b0; z1[j]     += xa[j] * b1; z2[j]     += xa[j] * b2;
          z0[4 + j] += xb[j] * b0; z1[4 + j] += xb[j] * b1; z2[4 + j] += xb[j] * b2;
        }
      }
    }

    // ---- A-frags from registers; B-frags read per-tile from LDS W2 (R12-validated in-loop) ----
    fv4 acc0 = (fv4){0.f, 0.f, 0.f, 0.f};
    fv4 acc1 = (fv4){0.f, 0.f, 0.f, 0.f};
#pragma unroll
    for (int kb = 0; kb < 3; ++kb) {
      const int cko = kb * 32 + grp * 4;
      sv8 bfr0, bfr1, afr;
      {
        const short* wr = &W2[rowl * PZB + cko];
        sv4 lo = *(const sv4*)(wr), hi = *(const sv4*)(wr + 16);
#pragma unroll
        for (int j = 0; j < 4; ++j) { bfr0[j] = lo[j]; bfr0[4 + j] = hi[j]; }
      }
      {
        const short* wr = &W2[(16 + rowl) * PZB + cko];
        sv4 lo = *(const sv4*)(wr), hi = *(const sv4*)(wr + 16);
#pragma unroll
        for (int j = 0; j < 4; ++j) { bfr1[j] = lo[j]; bfr1[4 + j] = hi[j]; }
      }
#pragma unroll
      for (int j = 0; j < 4; ++j) {
        float lo = (kb == 0) ? z0[j]     : (kb == 1) ? z1[j]     : z2[j];
        float hi = (kb == 0) ? z0[4 + j] : (kb == 1) ? z1[4 + j] : z2[4 + j];
        afr[j]     = f2bf(lo);
        afr[4 + j] = f2bf(hi);
      }
      acc0 = __builtin_amdgcn_mfma_f32_16x16x32_bf16(afr, bfr0, acc0, 0, 0, 0);
      acc1 = __builtin_amdgcn_mfma_f32_16x16x32_bf16(afr, bfr1, acc1, 0, 0, 0);
    }

    // ---- register epilogue (R12/R13-validated; folder lane of row == row) ----
#pragma unroll
    for (int r = 0; r < 4; ++r) {
      int row = grp * 4 + r;
      int fr = f0t + row;
      int nm = __shfl(nm_my, row, 64);
      float inv = 1.0f / (float)(nm > 1 ? nm : 1);
      if (fr < nf) {
        float v0 = fmaxf(acc0[r] * inv + bo0, 0.f);
        float v1 = fmaxf(acc1[r] * inv + bo1, 0.f);
        out[fr * 32 + rowl]      = v0;
        out[fr * 32 + 16 + rowl] = v1;
        s1l += v0; s2l += v0 * v0;
        s1h += v1; s2h += v1 * v1;
      }
    }
  }

  // ---- per-wave stats -> one partials column (validated reduce) ----
  s1l += __shfl_xor(s1l, 16, 64); s1l += __shfl_xor(s1l, 32, 64);
  s1h += __shfl_xor(s1h, 16, 64); s1h += __shfl_xor(s1h, 32, 64);
  s2l += __shfl_xor(s2l, 16, 64); s2l += __shfl_xor(s2l, 32, 64);
  s2h += __shfl_xor(s2h, 16, 64); s2h += __shfl_xor(s2h, 32, 64);
  if (grp == 0) {
    int w = blockIdx.x * 4 + wv;
    partials[(long)(rowl)      * nw + w] = s1l;
    partials[(long)(16 + rowl) * nw + w] = s1h;
    partials[(long)(32 + rowl) * nw + w] = s2l;
    partials[(long)(48 + rowl) * nw + w] = s2h;
  }
}

// ---------------- reduce partials -> stats[64] (sum[32], sumsq[32]) ----------------
__global__ __launch_bounds__(256) void k_reduce(const float* __restrict__ partials,
                                                int nw, float* __restrict__ stats) {
  __shared__ float sd[256];
  int c = blockIdx.x;
  const float* p = partials + (long)c * nw;
  float s = 0.f;
  for (int i = threadIdx.x; i < nw; i += 256) s += p[i];
  sd[threadIdx.x] = s; __syncthreads();
  for (int st = 128; st > 0; st >>= 1) {
    if (threadIdx.x < st) sd[threadIdx.x] += sd[threadIdx.x + st];
    __syncthreads();
  }
  if (threadIdx.x == 0) stats[c] = sd[0];
}

// ---------------- BN apply, in place on out ----------------
__global__ __launch_bounds__(256) void k_bn(float* __restrict__ out,
                                            const float* __restrict__ stats,
                                            const float* __restrict__ gamma,
                                            const float* __restrict__ beta, int nf) {
  __shared__ float sc[32], sh[32];
  if (threadIdx.x < 32) {
    int o = threadIdx.x;
    float inv_n = 1.0f / (float)nf;
    float mean = stats[o] * inv_n;
    float var = stats[32 + o] * inv_n - mean * mean;
    float rstd = rsqrtf(var + 1e-5f);
    float g = gamma[o] * rstd;
    sc[o] = g;
    sh[o] = beta[o] - mean * g;
  }
  __syncthreads();
  long total4 = (long)nf * 8;
  long idx0 = (long)blockIdx.x * 256 + threadIdx.x;
  int ob = ((int)idx0 & 7) * 4;           // constant per thread (stride % 8 == 0)
  fv4 scv = *(const fv4*)&sc[ob];
  fv4 shv = *(const fv4*)&sh[ob];
  for (long idx = idx0; idx < total4; idx += (long)gridDim.x * 256) {
    fv4 v = *((const fv4*)out + idx);
    v = v * scv + shv;
    *((fv4*)out + idx) = v;
  }
}

extern "C" void kernel_launch(void* const* d_in, const int* in_sizes, int n_in,
                              void* d_out, int out_size, void* d_ws, size_t ws_size,
                              hipStream_t stream) {
  const float* x     = (const float*)d_in[0];
  const float* bary  = (const float*)d_in[1];
  const int*   numt  = (const int*)d_in[2];
  const float* W     = (const float*)d_in[3];
  const float* bias  = (const float*)d_in[4];
  const float* gamma = (const float*)d_in[5];
  const float* beta  = (const float*)d_in[6];
  float* out = (float*)d_out;

  const int nf   = in_sizes[2];
  const int nt   = in_sizes[0] / 32;      // total samples
  const int nblk = (nf + SPAN - 1) / SPAN;
  const int nw   = nblk * 4;              // one partials column per wave
  const int nbS  = (nf + SCHUNK - 1) / SCHUNK;

  char* w = (char*)d_ws;
  int* offsets = (int*)w;
  size_t off1 = (4UL * (size_t)(nf + 1) + 255) & ~255UL;
  int* bsum = (int*)(w + off1);
  size_t off2 = (off1 + 4UL * (size_t)nbS + 255) & ~255UL;
  float* partials = (float*)(w + off2);
  size_t off3 = (off2 + 4UL * 64UL * (size_t)nw + 255) & ~255UL;
  float* stats = (float*)(w + off3);

  scan1<<<nbS, 256, 0, stream>>>(numt, nf, bsum);
  scan2<<<1, 256, 0, stream>>>(bsum, nbS);
  scan3<<<nbS, 256, 0, stream>>>(numt, nf, bsum, offsets);
  k_main<<<nblk, 256, 0, stream>>>(x, bary, W, bias, offsets, out, partials, nf, nt, nw);
  k_reduce<<<64, 256, 0, stream>>>(partials, nw, stats);
  k_bn<<<2048, 256, 0, stream>>>(out, stats, gamma, beta, nf);
}

// Round 19
// 95.073 us; speedup vs baseline: 1.0739x; 1.0193x over previous
//
#include <hip/hip_runtime.h>
#include <hip/hip_bf16.h>
#include <stdint.h>

typedef __attribute__((ext_vector_type(4))) float fv4;
typedef float fv4u __attribute__((ext_vector_type(4), aligned(4)));   // 4B-aligned vector load
typedef __attribute__((ext_vector_type(4))) short sv4;
typedef __attribute__((ext_vector_type(8))) short sv8;

#define SCHUNK 2048
#define NIT 8             // tiles per wave
#define SPAN (64 * NIT)   // facets per block
#define PZB 108           // W2 row pitch (shorts), validated

static __device__ __forceinline__ short f2bf(float f) {
  __hip_bfloat16 h = __float2bfloat16(f);   // HW v_cvt, RNE
  union { __hip_bfloat16 h; short s; } u; u.h = h;
  return u.s;
}

// ---------------- scan1: per-chunk sums (R1-validated) ----------------
__global__ __launch_bounds__(256) void scan1(const int* __restrict__ num, int nf,
                                             int* __restrict__ bsum) {
  __shared__ int sd[256];
  int b = blockIdx.x, tid = threadIdx.x;
  int base = b * SCHUNK + tid * 8;
  int s = 0;
#pragma unroll
  for (int j = 0; j < 8; ++j) { int i = base + j; if (i < nf) s += num[i]; }
  sd[tid] = s; __syncthreads();
  for (int st = 128; st > 0; st >>= 1) {
    if (tid < st) sd[tid] += sd[tid + st];
    __syncthreads();
  }
  if (tid == 0) bsum[b] = sd[0];
}

// ---------------- scan23: merged chunk-prefix (local re-scan of bsum) + offsets ----------------
// bsum stays read-only (raw chunk sums); each block recomputes the chunk-exclusive prefix
// locally with the SAME validated Hillis-Steele network scan2 used, then runs scan3's body.
__global__ __launch_bounds__(256) void scan23(const int* __restrict__ num, int nf,
                                              const int* __restrict__ bsum, int nb,
                                              int* __restrict__ offsets) {
  __shared__ int sb[256];
  __shared__ int sc_[256];
  int b = blockIdx.x, tid = threadIdx.x;

  // local inclusive scan of chunk sums (validated scan2 network; bsum read-only)
  int v = (tid < nb) ? bsum[tid] : 0;
  sb[tid] = v; __syncthreads();
  for (int off = 1; off < 256; off <<= 1) {
    int t = (tid >= off) ? sb[tid - off] : 0;
    __syncthreads();
    sb[tid] += t;
    __syncthreads();
  }
  const int chunk_base = sb[b] - bsum[b];   // exclusive prefix of chunk b (broadcast reads)

  // within-chunk scan + offsets write (R1-validated scan3 body, bsum[b] -> chunk_base)
  int base = b * SCHUNK + tid * 8;
  int loc[8]; int s = 0;
#pragma unroll
  for (int j = 0; j < 8; ++j) {
    loc[j] = (base + j < nf) ? num[base + j] : 0;
    s += loc[j];
  }
  sc_[tid] = s; __syncthreads();
  for (int off = 1; off < 256; off <<= 1) {
    int t = (tid >= off) ? sc_[tid - off] : 0;
    __syncthreads();
    sc_[tid] += t;
    __syncthreads();
  }
  int run = chunk_base + sc_[tid] - s;
#pragma unroll
  for (int j = 0; j < 8; ++j) {
    if (base + j < nf) offsets[base + j] = run;
    run += loc[j];
  }
  if (b == gridDim.x - 1 && tid == 255) offsets[nf] = run;
}

// ---------------- main: lane folds its own A-fragment; no LDS in the tile loop (R13 verbatim) ----------------
__global__ __launch_bounds__(256, 4) void k_main(
    const float* __restrict__ x, const float* __restrict__ bary,
    const float* __restrict__ W, const float* __restrict__ bias,
    const int* __restrict__ offsets, float* __restrict__ out,
    float* __restrict__ partials, int nf, int nt, int nw)
{
  __shared__ short W2[32 * PZB];       // 6912 B; read once per wave after prologue

  const int tid = threadIdx.x;
  const int lane = tid & 63;
  const int wv = tid >> 6;

  // ---- prologue: stage W2[o*PZB + k*32 + c] = bf16(W[o*96 + c*3 + k]) (validated) ----
  for (int idx = tid; idx < 3072; idx += 256) {
    int o = idx / 96;
    int ck = idx - o * 96;
    int k = ck >> 5, c = ck & 31;
    W2[o * PZB + ck] = f2bf(W[o * 96 + c * 3 + k]);
  }
  __syncthreads();   // the ONLY block barrier

  const int rowl = lane & 15;          // facet-in-tile AND output col
  const int grp = lane >> 4;           // fragment k-quad / epilogue row group
  const int cb_lo = grp * 4;           // fold channels low quad
  const int cb_hi = grp * 4 + 16;      // fold channels high quad
  const int blk0 = blockIdx.x * SPAN;

  // ---- hoist B-fragments (tile-invariant): 12 LDS reads once per wave (R12-validated) ----
  sv8 bfrA[3], bfrB[3];
#pragma unroll
  for (int kb = 0; kb < 3; ++kb) {
    const int cko = kb * 32 + grp * 4;
    {
      const short* wr = &W2[rowl * PZB + cko];
      sv4 lo = *(const sv4*)(wr), hi = *(const sv4*)(wr + 16);
#pragma unroll
      for (int j = 0; j < 4; ++j) { bfrA[kb][j] = lo[j]; bfrA[kb][4 + j] = hi[j]; }
    }
    {
      const short* wr = &W2[(16 + rowl) * PZB + cko];
      sv4 lo = *(const sv4*)(wr), hi = *(const sv4*)(wr + 16);
#pragma unroll
      for (int j = 0; j < 4; ++j) { bfrB[kb][j] = lo[j]; bfrB[kb][4 + j] = hi[j]; }
    }
  }

  float bo0 = bias[rowl];
  float bo1 = bias[16 + rowl];
  float s1l = 0.f, s1h = 0.f, s2l = 0.f, s2h = 0.f;

#pragma unroll 2
  for (int t = 0; t < NIT; ++t) {
    const int f0t = blk0 + t * 64 + wv * 16;
    const int f = f0t + rowl;
    const int fa = f < nf ? f : nf;
    const int fb = (f + 1) < nf ? (f + 1) : nf;

    // ---- batched loads: offsets AND speculative x/bary (R10/R12-validated pattern) ----
    const int st = offsets[fa];
    const int en = offsets[fb];
    const int s3 = 3 * f;
    const int sbase = (f < nf && s3 + 3 <= nt) ? s3 : 0;   // clamped, never OOB
    const float* xp0 = x + (size_t)(sbase + 0) * 32;
    const float* xp1 = x + (size_t)(sbase + 1) * 32;
    const float* xp2 = x + (size_t)(sbase + 2) * 32;
    fv4 x0a = *(const fv4*)(xp0 + cb_lo), x0b = *(const fv4*)(xp0 + cb_hi);
    fv4 x1a = *(const fv4*)(xp1 + cb_lo), x1b = *(const fv4*)(xp1 + cb_hi);
    fv4 x2a = *(const fv4*)(xp2 + cb_lo), x2b = *(const fv4*)(xp2 + cb_hi);
    // bary rows for samples sbase..sbase+2 are 9 contiguous floats
    const float* bp = bary + (size_t)sbase * 3;
    fv4u bv0 = *(const fv4u*)(bp);       // b00 b01 b02 b10
    fv4u bv1 = *(const fv4u*)(bp + 4);   // b11 b12 b20 b21
    float b22 = bp[8];
    float b00 = bv0[0], b01 = bv0[1], b02 = bv0[2];
    float b10 = bv0[3], b11 = bv1[0], b12 = bv1[1];
    float b20 = bv1[2], b21 = bv1[3];

    const int nm_my = en - st;

    // ---- fold (R12-validated FMA pattern; channel set = this lane's A-fragment) ----
    float z0[8], z1[8], z2[8];
#pragma unroll
    for (int j = 0; j < 8; ++j) { z0[j] = 0.f; z1[j] = 0.f; z2[j] = 0.f; }

    if (nm_my == 3 && st == s3) {
#pragma unroll
      for (int j = 0; j < 4; ++j) {
        z0[j]     += x0a[j] * b00; z1[j]     += x0a[j] * b01; z2[j]     += x0a[j] * b02;
        z0[4 + j] += x0b[j] * b00; z1[4 + j] += x0b[j] * b01; z2[4 + j] += x0b[j] * b02;
      }
#pragma unroll
      for (int j = 0; j < 4; ++j) {
        z0[j]     += x1a[j] * b10; z1[j]     += x1a[j] * b11; z2[j]     += x1a[j] * b12;
        z0[4 + j] += x1b[j] * b10; z1[4 + j] += x1b[j] * b11; z2[4 + j] += x1b[j] * b12;
      }
#pragma unroll
      for (int j = 0; j < 4; ++j) {
        z0[j]     += x2a[j] * b20; z1[j]     += x2a[j] * b21; z2[j]     += x2a[j] * b22;
        z0[4 + j] += x2b[j] * b20; z1[4 + j] += x2b[j] * b21; z2[4 + j] += x2b[j] * b22;
      }
    } else {
      // generic ragged path (validated FMA pattern, same channel set)
      for (int t2 = st; t2 < en; ++t2) {
        const float* xp = x + (size_t)t2 * 32;
        fv4 xa = *(const fv4*)(xp + cb_lo);
        fv4 xb = *(const fv4*)(xp + cb_hi);
        const float* bpp = bary + (size_t)t2 * 3;
        float b0 = bpp[0], b1 = bpp[1], b2 = bpp[2];
#pragma unroll
        for (int j = 0; j < 4; ++j) {
          z0[j]     += xa[j] * b0; z1[j]     += xa[j] * b1; z2[j]     += xa[j] * b2;
          z0[4 + j] += xb[j] * b0; z1[4 + j] += xb[j] * b1; z2[4 + j] += xb[j] * b2;
        }
      }
    }

    // ---- A-fragments directly from registers; MFMA (R12-validated) ----
    fv4 acc0 = (fv4){0.f, 0.f, 0.f, 0.f};
    fv4 acc1 = (fv4){0.f, 0.f, 0.f, 0.f};
#pragma unroll
    for (int kb = 0; kb < 3; ++kb) {
      sv8 afr;
#pragma unroll
      for (int j = 0; j < 4; ++j) {
        float lo = (kb == 0) ? z0[j]     : (kb == 1) ? z1[j]     : z2[j];
        float hi = (kb == 0) ? z0[4 + j] : (kb == 1) ? z1[4 + j] : z2[4 + j];
        afr[j]     = f2bf(lo);
        afr[4 + j] = f2bf(hi);
      }
      acc0 = __builtin_amdgcn_mfma_f32_16x16x32_bf16(afr, bfrA[kb], acc0, 0, 0, 0);
      acc1 = __builtin_amdgcn_mfma_f32_16x16x32_bf16(afr, bfrB[kb], acc1, 0, 0, 0);
    }

    // ---- register epilogue (R12-validated; folder lane of row == row) ----
#pragma unroll
    for (int r = 0; r < 4; ++r) {
      int row = grp * 4 + r;
      int fr = f0t + row;
      int nm = __shfl(nm_my, row, 64);
      float inv = 1.0f / (float)(nm > 1 ? nm : 1);
      if (fr < nf) {
        float v0 = fmaxf(acc0[r] * inv + bo0, 0.f);
        float v1 = fmaxf(acc1[r] * inv + bo1, 0.f);
        out[fr * 32 + rowl]      = v0;
        out[fr * 32 + 16 + rowl] = v1;
        s1l += v0; s2l += v0 * v0;
        s1h += v1; s2h += v1 * v1;
      }
    }
  }

  // ---- per-wave stats -> one partials column (validated reduce) ----
  s1l += __shfl_xor(s1l, 16, 64); s1l += __shfl_xor(s1l, 32, 64);
  s1h += __shfl_xor(s1h, 16, 64); s1h += __shfl_xor(s1h, 32, 64);
  s2l += __shfl_xor(s2l, 16, 64); s2l += __shfl_xor(s2l, 32, 64);
  s2h += __shfl_xor(s2h, 16, 64); s2h += __shfl_xor(s2h, 32, 64);
  if (grp == 0) {
    int w = blockIdx.x * 4 + wv;
    partials[(long)(rowl)      * nw + w] = s1l;
    partials[(long)(16 + rowl) * nw + w] = s1h;
    partials[(long)(32 + rowl) * nw + w] = s2l;
    partials[(long)(48 + rowl) * nw + w] = s2h;
  }
}

// ---------------- reduce partials -> stats[64] (sum[32], sumsq[32]) ----------------
__global__ __launch_bounds__(256) void k_reduce(const float* __restrict__ partials,
                                                int nw, float* __restrict__ stats) {
  __shared__ float sd[256];
  int c = blockIdx.x;
  const float* p = partials + (long)c * nw;
  float s = 0.f;
  for (int i = threadIdx.x; i < nw; i += 256) s += p[i];
  sd[threadIdx.x] = s; __syncthreads();
  for (int st = 128; st > 0; st >>= 1) {
    if (threadIdx.x < st) sd[threadIdx.x] += sd[threadIdx.x + st];
    __syncthreads();
  }
  if (threadIdx.x == 0) stats[c] = sd[0];
}

// ---------------- BN apply, in place on out ----------------
__global__ __launch_bounds__(256) void k_bn(float* __restrict__ out,
                                            const float* __restrict__ stats,
                                            const float* __restrict__ gamma,
                                            const float* __restrict__ beta, int nf) {
  __shared__ float sc[32], sh[32];
  if (threadIdx.x < 32) {
    int o = threadIdx.x;
    float inv_n = 1.0f / (float)nf;
    float mean = stats[o] * inv_n;
    float var = stats[32 + o] * inv_n - mean * mean;
    float rstd = rsqrtf(var + 1e-5f);
    float g = gamma[o] * rstd;
    sc[o] = g;
    sh[o] = beta[o] - mean * g;
  }
  __syncthreads();
  long total4 = (long)nf * 8;
  long idx0 = (long)blockIdx.x * 256 + threadIdx.x;
  int ob = ((int)idx0 & 7) * 4;           // constant per thread (stride % 8 == 0)
  fv4 scv = *(const fv4*)&sc[ob];
  fv4 shv = *(const fv4*)&sh[ob];
  for (long idx = idx0; idx < total4; idx += (long)gridDim.x * 256) {
    fv4 v = *((const fv4*)out + idx);
    v = v * scv + shv;
    *((fv4*)out + idx) = v;
  }
}

extern "C" void kernel_launch(void* const* d_in, const int* in_sizes, int n_in,
                              void* d_out, int out_size, void* d_ws, size_t ws_size,
                              hipStream_t stream) {
  const float* x     = (const float*)d_in[0];
  const float* bary  = (const float*)d_in[1];
  const int*   numt  = (const int*)d_in[2];
  const float* W     = (const float*)d_in[3];
  const float* bias  = (const float*)d_in[4];
  const float* gamma = (const float*)d_in[5];
  const float* beta  = (const float*)d_in[6];
  float* out = (float*)d_out;

  const int nf   = in_sizes[2];
  const int nt   = in_sizes[0] / 32;      // total samples
  const int nblk = (nf + SPAN - 1) / SPAN;
  const int nw   = nblk * 4;              // one partials column per wave
  const int nbS  = (nf + SCHUNK - 1) / SCHUNK;

  char* w = (char*)d_ws;
  int* offsets = (int*)w;
  size_t off1 = (4UL * (size_t)(nf + 1) + 255) & ~255UL;
  int* bsum = (int*)(w + off1);
  size_t off2 = (off1 + 4UL * (size_t)nbS + 255) & ~255UL;
  float* partials = (float*)(w + off2);
  size_t off3 = (off2 + 4UL * 64UL * (size_t)nw + 255) & ~255UL;
  float* stats = (float*)(w + off3);

  scan1<<<nbS, 256, 0, stream>>>(numt, nf, bsum);
  scan23<<<nbS, 256, 0, stream>>>(numt, nf, bsum, nbS, offsets);
  k_main<<<nblk, 256, 0, stream>>>(x, bary, W, bias, offsets, out, partials, nf, nt, nw);
  k_reduce<<<64, 256, 0, stream>>>(partials, nw, stats);
  k_bn<<<2048, 256, 0, stream>>>(out, stats, gamma, beta, nf);
}